// Round 4
// baseline (383.898 us; speedup 1.0000x reference)
//
#include <hip/hip_runtime.h>
#include <hip/hip_bf16.h>
#include <math.h>

#define Bn   128
#define Sn   512
#define HIDn 768
#define OUTn 200
#define MSEG 16
#define NPAD 208   // OUT padded to 13 MFMA n-tiles of 16
#define NT   13

typedef __attribute__((ext_vector_type(8))) short short8;
typedef __attribute__((ext_vector_type(4))) float f32x4;

// fp32 -> bf16 round-to-nearest-even (finite inputs)
static __device__ inline unsigned short f2bf(float f) {
  union { float f; unsigned u; } v; v.f = f;
  unsigned r = v.u + 0x7FFFu + ((v.u >> 16) & 1u);
  return (unsigned short)(r >> 16);
}

// saturating fast tanh: e = exp(-2|x|) in (0,1], never overflows
static __device__ inline float fast_tanh(float x) {
  float t = fabsf(x);
  float e = __expf(-2.f * t);
  float r = (1.f - e) * __builtin_amdgcn_rcpf(1.f + e);
  return copysignf(r, x);
}

// one-time: WhT[n][k] = bf16(Wh[k][n]), zero-padded rows 200..207; vP padded v.
// Fully parallel: one block per 16x16 tile (13 * 48 = 624 blocks).
__global__ __launch_bounds__(256) void setup_kernel(
    const float* __restrict__ Wh, const float* __restrict__ v,
    unsigned short* __restrict__ WhT, float* __restrict__ vP) {
  __shared__ float tile[16][17];
  int n0 = (blockIdx.x % 13) * 16;
  int k0 = (blockIdx.x / 13) * 16;
  int tid = threadIdx.x;
  if (blockIdx.x == 0 && tid < NPAD) vP[tid] = (tid < OUTn) ? v[tid] : 0.f;
  int tk = tid >> 4, tn = tid & 15;
  float val = 0.f;
  int n = n0 + tn;
  if (n < OUTn) val = Wh[(size_t)(k0 + tk) * OUTn + n];
  tile[tk][tn] = val;
  __syncthreads();
  int tn2 = tid >> 4, tk2 = tid & 15;
  WhT[(size_t)(n0 + tn2) * HIDn + k0 + tk2] = f2bf(tile[tk2][tn2]);
}

// biasP[b][n] = b[n] + u[b]@Wu[:,n] + p[b]@Wp[:,n], zero-padded to NPAD
__global__ __launch_bounds__(256) void bias_kernel(
    const float* __restrict__ u, const float* __restrict__ p,
    const float* __restrict__ Wu, const float* __restrict__ Wp,
    const float* __restrict__ bvec, float* __restrict__ biasP) {
  int b = blockIdx.x;
  __shared__ float ul[OUTn], pl[OUTn];
  int tid = threadIdx.x;
  if (tid < OUTn) { ul[tid] = u[b * OUTn + tid]; pl[tid] = p[b * OUTn + tid]; }
  __syncthreads();
  if (tid < NPAD) {
    float s0 = 0.f, s1 = 0.f;
    if (tid < OUTn) {
      s0 = bvec[tid];
      for (int k = 0; k < OUTn; k += 2) {
        s0 += ul[k] * Wu[k * OUTn + tid] + pl[k] * Wp[k * OUTn + tid];
        s1 += ul[k + 1] * Wu[(k + 1) * OUTn + tid] + pl[k + 1] * Wp[(k + 1) * OUTn + tid];
      }
    }
    biasP[(size_t)b * NPAD + tid] = s0 + s1;
  }
}

// Fused: scores via bf16 MFMA (A from HBM, B direct from L2-resident WhT —
// NO barriers in the K-loop), per-wave segment softmax, weighted-sum output.
// Block = 128 rows of one batch b; wave w owns rows [w*32, w*32+32) = one segment.
__global__ __launch_bounds__(256) void fused_kernel(
    const float* __restrict__ H, const unsigned short* __restrict__ WhT,
    const float* __restrict__ biasP, const float* __restrict__ vP,
    const int* __restrict__ offs, float* __restrict__ out) {
  __shared__ float al[128];                 // per-wave alphas
  int tid = threadIdx.x, wave = tid >> 6, lane = tid & 63;
  int quad = lane >> 4, l16 = lane & 15;
  int m0 = blockIdx.x * 128;
  int b = m0 >> 9;
  int s0 = m0 & 511;

  f32x4 acc[2][NT];
  for (int mt = 0; mt < 2; ++mt)
    for (int nt = 0; nt < NT; ++nt) acc[mt][nt] = (f32x4){0.f, 0.f, 0.f, 0.f};

  const float* Abase = H + (size_t)(m0 + wave * 32 + l16) * HIDn + quad * 8;
  const unsigned short* Bbase = WhT + (size_t)l16 * HIDn + quad * 8;

  for (int k0 = 0; k0 < HIDn; k0 += 32) {
    float4 f[2][2];
#pragma unroll
    for (int mt = 0; mt < 2; ++mt) {
      const float* ap = Abase + (size_t)mt * 16 * HIDn + k0;
      f[mt][0] = *(const float4*)ap;
      f[mt][1] = *(const float4*)(ap + 4);
    }
    short8 bfr[NT];
#pragma unroll
    for (int nt = 0; nt < NT; ++nt)
      bfr[nt] = *(const short8*)(Bbase + (size_t)nt * 16 * HIDn + k0);

    short8 a[2];
#pragma unroll
    for (int mt = 0; mt < 2; ++mt) {
      short8 t;
      t[0] = f2bf(f[mt][0].x); t[1] = f2bf(f[mt][0].y);
      t[2] = f2bf(f[mt][0].z); t[3] = f2bf(f[mt][0].w);
      t[4] = f2bf(f[mt][1].x); t[5] = f2bf(f[mt][1].y);
      t[6] = f2bf(f[mt][1].z); t[7] = f2bf(f[mt][1].w);
      a[mt] = t;
    }
#pragma unroll
    for (int nt = 0; nt < NT; ++nt) {
      acc[0][nt] = __builtin_amdgcn_mfma_f32_16x16x32_bf16(a[0], bfr[nt], acc[0][nt], 0, 0, 0);
      acc[1][nt] = __builtin_amdgcn_mfma_f32_16x16x32_bf16(a[1], bfr[nt], acc[1][nt], 0, 0, 0);
    }
  }

  // ---- scores: sc[mt][r] = v . tanh(C + bias), reduced over l16
  const float* bp = biasP + (size_t)b * NPAD;
  float sc[2][4];
#pragma unroll
  for (int mt = 0; mt < 2; ++mt) {
#pragma unroll
    for (int r = 0; r < 4; ++r) {
      float s = 0.f;
#pragma unroll
      for (int nt = 0; nt < NT; ++nt) {
        int n = nt * 16 + l16;
        s += fast_tanh(acc[mt][nt][r] + bp[n]) * vP[n];
      }
      s += __shfl_xor(s, 1); s += __shfl_xor(s, 2);
      s += __shfl_xor(s, 4); s += __shfl_xor(s, 8);
      sc[mt][r] = s;  // score for row wave*32 + mt*16 + quad*4 + r
    }
  }

  // ---- per-wave segment softmax (wave w owns segment seg)
  int seg = (s0 >> 5) + wave;
  int beg = offs[b * (MSEG + 1) + seg];
  int nxt = offs[b * (MSEG + 1) + seg + 1];
  bool valid = (beg != -1);
  int end = (nxt == -1) ? Sn : nxt - 1;

  float x[2][4];
  float mx = -INFINITY;
#pragma unroll
  for (int mt = 0; mt < 2; ++mt)
#pragma unroll
    for (int r = 0; r < 4; ++r) {
      int row = s0 + wave * 32 + mt * 16 + quad * 4 + r;
      bool in = valid && row >= beg && row < end;
      x[mt][r] = in ? sc[mt][r] : -INFINITY;
      mx = fmaxf(mx, x[mt][r]);
    }
  mx = fmaxf(mx, __shfl_xor(mx, 16));
  mx = fmaxf(mx, __shfl_xor(mx, 32));
  float mm = (mx > -1e30f) ? mx : 0.f;

  float e[2][4], ls = 0.f;
#pragma unroll
  for (int mt = 0; mt < 2; ++mt)
#pragma unroll
    for (int r = 0; r < 4; ++r) {
      e[mt][r] = __expf(x[mt][r] - mm);  // exp(-inf) = 0 handles masking
      ls += e[mt][r];
    }
  ls += __shfl_xor(ls, 16);
  ls += __shfl_xor(ls, 32);
  float inv = (ls > 0.f) ? 1.f / ls : 0.f;

  if (l16 == 0) {
#pragma unroll
    for (int mt = 0; mt < 2; ++mt)
#pragma unroll
      for (int r = 0; r < 4; ++r)
        al[wave * 32 + mt * 16 + quad * 4 + r] = e[mt][r] * inv;
  }
  // al written+read by same wave only -> no __syncthreads needed

  // ---- weighted sum over the wave's 32 rows (L2-hot: just streamed by GEMM)
  const float4* Hrow = (const float4*)(H + (size_t)(b * Sn + s0 + wave * 32) * HIDn);
  float4 o0 = {0,0,0,0}, o1 = {0,0,0,0}, o2 = {0,0,0,0};
  for (int i = 0; i < 32; ++i) {
    float a = al[wave * 32 + i];       // LDS broadcast, wave-uniform
    if (a != 0.f) {                    // uniform branch (skips masked row 31)
      const float4* hp = Hrow + (size_t)i * (HIDn / 4);
      float4 h0 = hp[lane], h1 = hp[lane + 64], h2 = hp[lane + 128];
      o0.x += a * h0.x; o0.y += a * h0.y; o0.z += a * h0.z; o0.w += a * h0.w;
      o1.x += a * h1.x; o1.y += a * h1.y; o1.z += a * h1.z; o1.w += a * h1.w;
      o2.x += a * h2.x; o2.y += a * h2.y; o2.z += a * h2.z; o2.w += a * h2.w;
    }
  }
  float4* op = (float4*)(out + ((size_t)b * MSEG + seg) * HIDn);
  op[lane] = o0; op[lane + 64] = o1; op[lane + 128] = o2;
}

extern "C" void kernel_launch(void* const* d_in, const int* in_sizes, int n_in,
                              void* d_out, int out_size, void* d_ws, size_t ws_size,
                              hipStream_t stream) {
  const float* H    = (const float*)d_in[0];
  const float* u    = (const float*)d_in[1];
  const float* p    = (const float*)d_in[2];
  const float* Wh   = (const float*)d_in[3];
  const float* Wu   = (const float*)d_in[4];
  const float* Wp   = (const float*)d_in[5];
  const float* v    = (const float*)d_in[6];
  const float* bvec = (const float*)d_in[7];
  const int*   offs = (const int*)d_in[8];
  float* out = (float*)d_out;

  // ws layout: biasP[128*208] | vP[208] | WhT (bf16 208*768)
  float* biasP = (float*)d_ws;
  float* vP    = biasP + (size_t)Bn * NPAD;
  unsigned short* WhT = (unsigned short*)(vP + NPAD);

  setup_kernel<<<13 * 48, 256, 0, stream>>>(Wh, v, WhT, vP);
  bias_kernel<<<Bn, 256, 0, stream>>>(u, p, Wu, Wp, bvec, biasP);
  fused_kernel<<<(Bn * Sn) / 128, 256, 0, stream>>>(H, WhT, biasP, vP, offs, out);
}

// Round 5
// 359.399 us; speedup vs baseline: 1.0682x; 1.0682x over previous
//
#include <hip/hip_runtime.h>
#include <hip/hip_bf16.h>
#include <math.h>

#define Bn   128
#define Sn   512
#define HIDn 768
#define OUTn 200
#define MSEG 16
#define NPAD 208   // OUT padded to 13 MFMA n-tiles of 16
#define NT   13
#define KIT  (HIDn / 32)   // 24 k-iterations

typedef __attribute__((ext_vector_type(8))) short short8;
typedef __attribute__((ext_vector_type(4))) float f32x4;

// fp32 -> bf16 round-to-nearest-even (finite inputs)
static __device__ inline unsigned short f2bf(float f) {
  union { float f; unsigned u; } v; v.f = f;
  unsigned r = v.u + 0x7FFFu + ((v.u >> 16) & 1u);
  return (unsigned short)(r >> 16);
}

// saturating fast tanh: e = exp(-2|x|) in (0,1], never overflows
static __device__ inline float fast_tanh(float x) {
  float t = fabsf(x);
  float e = __expf(-2.f * t);
  float r = (1.f - e) * __builtin_amdgcn_rcpf(1.f + e);
  return copysignf(r, x);
}

// one-time: WhF = bf16(Wh^T) in MFMA B-fragment order:
// elem (n,k) -> ((k>>5)*NT + (n>>4))*512 + ((k>>3)&3)*128 + (n&15)*8 + (k&7)
// so per (k-tile, n-tile) a wave's fragment is one contiguous 1 KB chunk at
// base + lane*16.  Rows 200..207 zero-padded.  vP = v zero-padded to NPAD.
__global__ __launch_bounds__(256) void setup_kernel(
    const float* __restrict__ Wh, const float* __restrict__ v,
    unsigned short* __restrict__ WhF, float* __restrict__ vP) {
  int idx = blockIdx.x * 256 + threadIdx.x;   // grid 624 -> 159744 = NPAD*HIDn
  if (blockIdx.x == 0 && threadIdx.x < NPAD)
    vP[threadIdx.x] = (threadIdx.x < OUTn) ? v[threadIdx.x] : 0.f;
  if (idx < NPAD * HIDn) {
    int n = idx / HIDn;
    int k = idx - n * HIDn;
    float val = (n < OUTn) ? Wh[(size_t)k * OUTn + n] : 0.f;
    size_t d = ((size_t)(k >> 5) * NT + (n >> 4)) * 512
             + ((k >> 3) & 3) * 128 + (n & 15) * 8 + (k & 7);
    WhF[d] = f2bf(val);
  }
}

// biasP[b][n] = b[n] + u[b]@Wu[:,n] + p[b]@Wp[:,n], zero-padded to NPAD
__global__ __launch_bounds__(256) void bias_kernel(
    const float* __restrict__ u, const float* __restrict__ p,
    const float* __restrict__ Wu, const float* __restrict__ Wp,
    const float* __restrict__ bvec, float* __restrict__ biasP) {
  int b = blockIdx.x;
  __shared__ float ul[OUTn], pl[OUTn];
  int tid = threadIdx.x;
  if (tid < OUTn) { ul[tid] = u[b * OUTn + tid]; pl[tid] = p[b * OUTn + tid]; }
  __syncthreads();
  if (tid < NPAD) {
    float s0 = 0.f, s1 = 0.f;
    if (tid < OUTn) {
      s0 = bvec[tid];
      for (int k = 0; k < OUTn; k += 2) {
        s0 += ul[k] * Wu[k * OUTn + tid] + pl[k] * Wp[k * OUTn + tid];
        s1 += ul[k + 1] * Wu[(k + 1) * OUTn + tid] + pl[k + 1] * Wp[(k + 1) * OUTn + tid];
      }
    }
    biasP[(size_t)b * NPAD + tid] = s0 + s1;
  }
}

// Fused: barrier-free bf16-MFMA score GEMM (A prefetched from HBM, B as
// coalesced fragment loads from L2-resident WhF), per-wave segment softmax,
// weighted-sum output.  Block = 128 rows of batch b; wave w owns rows
// [w*32, w*32+32) = exactly one segment.
__global__ __launch_bounds__(256, 2) void fused_kernel(
    const float* __restrict__ H, const unsigned short* __restrict__ WhF,
    const float* __restrict__ biasP, const float* __restrict__ vP,
    const int* __restrict__ offs, float* __restrict__ out) {
  __shared__ float al[128];
  int tid = threadIdx.x, wave = tid >> 6, lane = tid & 63;
  int quad = lane >> 4, l16 = lane & 15;
  int m0 = blockIdx.x * 128;
  int b = m0 >> 9;
  int s0 = m0 & 511;

  f32x4 acc[2][NT];
  for (int mt = 0; mt < 2; ++mt)
    for (int nt = 0; nt < NT; ++nt) acc[mt][nt] = (f32x4){0.f, 0.f, 0.f, 0.f};

  const float* Abase = H + (size_t)(m0 + wave * 32 + l16) * HIDn + quad * 8;
  const short8* Bw = (const short8*)WhF + lane;  // + (it*NT+nt)*64 per fragment

  float4 f[2][2][2];  // [buf][mt][half]
#pragma unroll
  for (int mt = 0; mt < 2; ++mt) {
    const float* ap = Abase + (size_t)mt * 16 * HIDn;
    f[0][mt][0] = *(const float4*)ap;
    f[0][mt][1] = *(const float4*)(ap + 4);
  }

#pragma unroll
  for (int it = 0; it < KIT; ++it) {
    int cur = it & 1;
    // prefetch next iteration's A (stays in flight across this iter's MFMA)
    if (it + 1 < KIT) {
#pragma unroll
      for (int mt = 0; mt < 2; ++mt) {
        const float* ap = Abase + (size_t)mt * 16 * HIDn + (it + 1) * 32;
        f[1 - cur][mt][0] = *(const float4*)ap;
        f[1 - cur][mt][1] = *(const float4*)(ap + 4);
      }
    }
    // B fragments: one fully-coalesced 16B/lane load per n-tile (L2/L1-hot)
    short8 bfr[NT];
#pragma unroll
    for (int nt = 0; nt < NT; ++nt)
      bfr[nt] = Bw[(it * NT + nt) * 64];

    short8 a[2];
#pragma unroll
    for (int mt = 0; mt < 2; ++mt) {
      short8 t;
      t[0] = f2bf(f[cur][mt][0].x); t[1] = f2bf(f[cur][mt][0].y);
      t[2] = f2bf(f[cur][mt][0].z); t[3] = f2bf(f[cur][mt][0].w);
      t[4] = f2bf(f[cur][mt][1].x); t[5] = f2bf(f[cur][mt][1].y);
      t[6] = f2bf(f[cur][mt][1].z); t[7] = f2bf(f[cur][mt][1].w);
      a[mt] = t;
    }
#pragma unroll
    for (int nt = 0; nt < NT; ++nt) {
      acc[0][nt] = __builtin_amdgcn_mfma_f32_16x16x32_bf16(a[0], bfr[nt], acc[0][nt], 0, 0, 0);
      acc[1][nt] = __builtin_amdgcn_mfma_f32_16x16x32_bf16(a[1], bfr[nt], acc[1][nt], 0, 0, 0);
    }
  }

  // ---- scores: sc[mt][r] = v . tanh(C + bias), reduced over l16
  const float* bp = biasP + (size_t)b * NPAD;
  float sc[2][4];
#pragma unroll
  for (int mt = 0; mt < 2; ++mt) {
#pragma unroll
    for (int r = 0; r < 4; ++r) {
      float s = 0.f;
#pragma unroll
      for (int nt = 0; nt < NT; ++nt) {
        int n = nt * 16 + l16;
        s += fast_tanh(acc[mt][nt][r] + bp[n]) * vP[n];
      }
      s += __shfl_xor(s, 1); s += __shfl_xor(s, 2);
      s += __shfl_xor(s, 4); s += __shfl_xor(s, 8);
      sc[mt][r] = s;  // score for row wave*32 + mt*16 + quad*4 + r
    }
  }

  // ---- per-wave segment softmax (wave w owns segment seg)
  int seg = (s0 >> 5) + wave;
  int beg = offs[b * (MSEG + 1) + seg];
  int nxt = offs[b * (MSEG + 1) + seg + 1];
  bool valid = (beg != -1);
  int end = (nxt == -1) ? Sn : nxt - 1;

  float x[2][4];
  float mx = -INFINITY;
#pragma unroll
  for (int mt = 0; mt < 2; ++mt)
#pragma unroll
    for (int r = 0; r < 4; ++r) {
      int row = s0 + wave * 32 + mt * 16 + quad * 4 + r;
      bool in = valid && row >= beg && row < end;
      x[mt][r] = in ? sc[mt][r] : -INFINITY;
      mx = fmaxf(mx, x[mt][r]);
    }
  mx = fmaxf(mx, __shfl_xor(mx, 16));
  mx = fmaxf(mx, __shfl_xor(mx, 32));
  float mm = (mx > -1e30f) ? mx : 0.f;

  float e[2][4], ls = 0.f;
#pragma unroll
  for (int mt = 0; mt < 2; ++mt)
#pragma unroll
    for (int r = 0; r < 4; ++r) {
      e[mt][r] = __expf(x[mt][r] - mm);  // exp(-inf)=0 handles masking
      ls += e[mt][r];
    }
  ls += __shfl_xor(ls, 16);
  ls += __shfl_xor(ls, 32);
  float inv = (ls > 0.f) ? 1.f / ls : 0.f;

  if (l16 == 0) {
#pragma unroll
    for (int mt = 0; mt < 2; ++mt)
#pragma unroll
      for (int r = 0; r < 4; ++r)
        al[wave * 32 + mt * 16 + quad * 4 + r] = e[mt][r] * inv;
  }
  // al written+read by same wave only -> no __syncthreads needed

  // ---- weighted sum over the wave's 32 rows
  const float4* Hrow = (const float4*)(H + (size_t)(b * Sn + s0 + wave * 32) * HIDn);
  float4 o0 = {0,0,0,0}, o1 = {0,0,0,0}, o2 = {0,0,0,0};
  for (int i = 0; i < 32; ++i) {
    float a = al[wave * 32 + i];       // LDS broadcast, wave-uniform
    if (a != 0.f) {                    // uniform branch (skips masked row 31)
      const float4* hp = Hrow + (size_t)i * (HIDn / 4);
      float4 h0 = hp[lane], h1 = hp[lane + 64], h2 = hp[lane + 128];
      o0.x += a * h0.x; o0.y += a * h0.y; o0.z += a * h0.z; o0.w += a * h0.w;
      o1.x += a * h1.x; o1.y += a * h1.y; o1.z += a * h1.z; o1.w += a * h1.w;
      o2.x += a * h2.x; o2.y += a * h2.y; o2.z += a * h2.z; o2.w += a * h2.w;
    }
  }
  float4* op = (float4*)(out + ((size_t)b * MSEG + seg) * HIDn);
  op[lane] = o0; op[lane + 64] = o1; op[lane + 128] = o2;
}

extern "C" void kernel_launch(void* const* d_in, const int* in_sizes, int n_in,
                              void* d_out, int out_size, void* d_ws, size_t ws_size,
                              hipStream_t stream) {
  const float* H    = (const float*)d_in[0];
  const float* u    = (const float*)d_in[1];
  const float* p    = (const float*)d_in[2];
  const float* Wh   = (const float*)d_in[3];
  const float* Wu   = (const float*)d_in[4];
  const float* Wp   = (const float*)d_in[5];
  const float* v    = (const float*)d_in[6];
  const float* bvec = (const float*)d_in[7];
  const int*   offs = (const int*)d_in[8];
  float* out = (float*)d_out;

  // ws layout: biasP[128*208] | vP[208] | WhF (bf16 208*768, fragment order)
  float* biasP = (float*)d_ws;
  float* vP    = biasP + (size_t)Bn * NPAD;
  unsigned short* WhF = (unsigned short*)(vP + NPAD);

  setup_kernel<<<(NPAD * HIDn + 255) / 256, 256, 0, stream>>>(Wh, v, WhF, vP);
  bias_kernel<<<Bn, 256, 0, stream>>>(u, p, Wu, Wp, bvec, biasP);
  fused_kernel<<<(Bn * Sn) / 128, 256, 0, stream>>>(H, WhF, biasP, vP, offs, out);
}